// Round 1
// 2231.364 us; speedup vs baseline: 1.0849x; 1.0849x over previous
//
#include <hip/hip_runtime.h>
#include <cstdint>
#include <cmath>

// LLaMA block forward, B=1 S=2048 D=4096 H=32 HD=128 FF=11008, fp32 in/out,
// bf16 MFMA internal compute (harness threshold 0.127 is bf16-scale).
//
// Pipeline:
//   1. transpose-convert 7 weight mats fp32 (K,N) -> bf16 (N,K)  [B^T for GEMMs]
//   2. rmsnorm(x) -> xn bf16
//   3. q = xn@wq, k = xn@wk (bf16 GEMM);  v GEMM stores transposed -> vt (D,S)
//   4. rope(q,k) in place
//   5. flash attention (online softmax, no S*S materialization) -> attn bf16
//      - causal-fold pairing: block handles q-tiles {x, 15-x} -> uniform work
//      - double-buffered K/V LDS, reg-staged prefetch, 1 barrier/iter
//   6. attn@wo + x -> x2 fp32
//   7. rmsnorm(x2) -> xn2; g = xn2@wg, u = xn2@w1; h = silu(g)*u; h@w2 + x2 -> out

typedef unsigned short u16;
typedef unsigned int u32;
typedef __bf16 bf16x8 __attribute__((ext_vector_type(8)));
typedef float f32x4 __attribute__((ext_vector_type(4)));

__device__ __forceinline__ float bf2f(u16 u) {
    u32 x = ((u32)u) << 16; float f; __builtin_memcpy(&f, &x, 4); return f;
}
__device__ __forceinline__ u16 f2bf(float f) {
    u32 x; __builtin_memcpy(&x, &f, 4);
    u32 r = x + 0x7fff + ((x >> 16) & 1);   // RNE
    return (u16)(r >> 16);
}

// async global->LDS, 16B per lane (CK-style casts)
__device__ __forceinline__ void g2l16(const void* g, void* l) {
    auto* gp = reinterpret_cast<const u32*>(reinterpret_cast<uintptr_t>(g));
    auto* lp = reinterpret_cast<__attribute__((address_space(3))) u32*>(
        reinterpret_cast<uintptr_t>(l));
    __builtin_amdgcn_global_load_lds(gp, lp, 16, 0, 0);
}

// ---------------------------------------------------------------------------
// Transpose + convert: in fp32 (K,N) row-major -> out bf16 (N,K) row-major.
// 64(k) x 32(n) tiles, block (32,8). Reads coalesced fp32, writes ushort2.
__global__ __launch_bounds__(256) void transpose_f32_bf16(
    const float* __restrict__ in, u16* __restrict__ out, int K, int N) {
    __shared__ float tile[64][33];
    const int k0 = blockIdx.y * 64, n0 = blockIdx.x * 32;
    const int x = threadIdx.x, y = threadIdx.y;
#pragma unroll
    for (int i = 0; i < 8; i++) {
        int kr = y + i * 8;
        tile[kr][x] = in[(size_t)(k0 + kr) * N + n0 + x];
    }
    __syncthreads();
#pragma unroll
    for (int i = 0; i < 4; i++) {
        int nr = y + i * 8;
        u32 pk = (u32)f2bf(tile[2 * x][nr]) | ((u32)f2bf(tile[2 * x + 1][nr]) << 16);
        ((u32*)(out + (size_t)(n0 + nr) * K + k0))[x] = pk;
    }
}

// ---------------------------------------------------------------------------
// RMSNorm: fp32 in (row of 4096) -> bf16 out. One block per row.
__global__ __launch_bounds__(256) void rmsnorm_kernel(
    const float* __restrict__ x, const float* __restrict__ w, u16* __restrict__ o) {
    const int row = blockIdx.x;
    const float4* xr = (const float4*)(x + (size_t)row * 4096);
    float4 v[4];
    float ss = 0.f;
#pragma unroll
    for (int i = 0; i < 4; i++) {
        v[i] = xr[threadIdx.x + 256 * i];
        ss += v[i].x * v[i].x + v[i].y * v[i].y + v[i].z * v[i].z + v[i].w * v[i].w;
    }
#pragma unroll
    for (int off = 32; off > 0; off >>= 1) ss += __shfl_down(ss, off, 64);
    __shared__ float ws4[4];
    if ((threadIdx.x & 63) == 0) ws4[threadIdx.x >> 6] = ss;
    __syncthreads();
    float inv = rsqrtf((ws4[0] + ws4[1] + ws4[2] + ws4[3]) * (1.f / 4096.f) + 1e-5f);
    const float4* wr = (const float4*)w;
    u32* orow = (u32*)(o + (size_t)row * 4096);
#pragma unroll
    for (int i = 0; i < 4; i++) {
        float4 wv = wr[threadIdx.x + 256 * i];
        u32 lo = (u32)f2bf(v[i].x * inv * wv.x) | ((u32)f2bf(v[i].y * inv * wv.y) << 16);
        u32 hi = (u32)f2bf(v[i].z * inv * wv.z) | ((u32)f2bf(v[i].w * inv * wv.w) << 16);
        int idx = (threadIdx.x + 256 * i) * 2;
        orow[idx] = lo; orow[idx + 1] = hi;
    }
}

// ---------------------------------------------------------------------------
// RoPE in place on q (blockIdx.y=0) / k (blockIdx.y=1). One block per position.
__global__ __launch_bounds__(256) void rope_kernel(u16* __restrict__ q, u16* __restrict__ k) {
    const int s = blockIdx.x;
    u32* pr = (u32*)((blockIdx.y ? k : q) + (size_t)s * 4096);
#pragma unroll
    for (int it = 0; it < 8; it++) {
        int pidx = threadIdx.x + it * 256;      // pair index within row (0..2047)
        int i = pidx & 63;                      // freq index within head
        float ang = (float)s * expf(-(float)i * 0.14391156832817f); // 10000^(-2i/128)
        float sn, cs; sincosf(ang, &sn, &cs);
        u32 u = pr[pidx];
        float x1 = bf2f((u16)u), x2 = bf2f((u16)(u >> 16));
        pr[pidx] = (u32)f2bf(x1 * cs - x2 * sn) | ((u32)f2bf(x1 * sn + x2 * cs) << 16);
    }
}

// ---------------------------------------------------------------------------
// SiLU(g) * u elementwise, bf16, 8 elems/thread.
__global__ __launch_bounds__(256) void silu_mul_kernel(
    const u16* __restrict__ g, const u16* __restrict__ u, u16* __restrict__ o) {
    size_t i = (size_t)blockIdx.x * 256 + threadIdx.x;
    uint4 gv = ((const uint4*)g)[i];
    uint4 uv = ((const uint4*)u)[i];
    const u32* gp = (const u32*)&gv;
    const u32* up = (const u32*)&uv;
    u32 rr[4];
#pragma unroll
    for (int j = 0; j < 4; j++) {
        float g0 = bf2f((u16)gp[j]), g1 = bf2f((u16)(gp[j] >> 16));
        float u0 = bf2f((u16)up[j]), u1 = bf2f((u16)(up[j] >> 16));
        float s0 = g0 / (1.f + __expf(-g0)) * u0;
        float s1 = g1 / (1.f + __expf(-g1)) * u1;
        rr[j] = (u32)f2bf(s0) | ((u32)f2bf(s1) << 16);
    }
    ((uint4*)o)[i] = *(const uint4*)rr;
}

// ---------------------------------------------------------------------------
// GEMM: C(MxN) = A(MxK, row-major bf16) * B (given as B^T: (N,K) row-major bf16).
// 128x128 tile per 256-thread block, BK=32, mfma_f32_16x16x32_bf16, 4x4 frags/wave.
// EPI 0: store bf16 C[m][n].  EPI 1: store bf16 transposed C[n][m] (ldc = M-stride).
// EPI 2: store fp32 C[m][n] = acc + res[m][n].
template <int EPI>
__global__ __launch_bounds__(256) void gemm_bt(
    const u16* __restrict__ A, const u16* __restrict__ BT, void* __restrict__ Cout,
    const float* __restrict__ res, int M, int N, int K, int lda, int ldb, int ldc) {
    (void)M; (void)N;
    __shared__ u16 As[128 * 32];
    __shared__ u16 Bs[128 * 32];
    const int tid = threadIdx.x;
    const int lane = tid & 63, wave = tid >> 6;
    const int m0 = blockIdx.y * 128, n0 = blockIdx.x * 128;
    const int wm = (wave >> 1) * 64, wn = (wave & 1) * 64;
    const int gc = lane & 15, grp = lane >> 4;

    // staging: thread t stages chunk t and t+256; chunk c -> row c>>2, koff (c&3)*8
    const u16* ga0 = A + (size_t)(m0 + (tid >> 2)) * lda + (tid & 3) * 8;
    const u16* ga1 = ga0 + (size_t)64 * lda;
    const u16* gb0 = BT + (size_t)(n0 + (tid >> 2)) * ldb + (tid & 3) * 8;
    const u16* gb1 = gb0 + (size_t)64 * ldb;
    u16* la0 = As + tid * 8;
    u16* la1 = As + tid * 8 + 2048;
    u16* lb0 = Bs + tid * 8;
    u16* lb1 = Bs + tid * 8 + 2048;

    f32x4 acc[4][4] = {};

    for (int k0 = 0; k0 < K; k0 += 32) {
        g2l16(ga0, la0); g2l16(ga1, la1);
        g2l16(gb0, lb0); g2l16(gb1, lb1);
        ga0 += 32; ga1 += 32; gb0 += 32; gb1 += 32;
        __syncthreads();
        bf16x8 af[4], bfr[4];
#pragma unroll
        for (int t = 0; t < 4; t++) {
            af[t]  = *(const bf16x8*)(As + (wm + t * 16 + gc) * 32 + grp * 8);
            bfr[t] = *(const bf16x8*)(Bs + (wn + t * 16 + gc) * 32 + grp * 8);
        }
#pragma unroll
        for (int mt = 0; mt < 4; mt++)
#pragma unroll
            for (int nt = 0; nt < 4; nt++)
                acc[mt][nt] = __builtin_amdgcn_mfma_f32_16x16x32_bf16(
                    af[mt], bfr[nt], acc[mt][nt], 0, 0, 0);
        __syncthreads();
    }

    // epilogue; C/D layout: col = lane&15, row = (lane>>4)*4 + reg
#pragma unroll
    for (int mt = 0; mt < 4; mt++) {
#pragma unroll
        for (int nt = 0; nt < 4; nt++) {
            int row0 = m0 + wm + mt * 16 + grp * 4;
            int col = n0 + wn + nt * 16 + gc;
            if (EPI == 0) {
                u16* C = (u16*)Cout;
#pragma unroll
                for (int r = 0; r < 4; r++)
                    C[(size_t)(row0 + r) * ldc + col] = f2bf(acc[mt][nt][r]);
            } else if (EPI == 1) {
                u16* C = (u16*)Cout;
                u32 p0 = (u32)f2bf(acc[mt][nt][0]) | ((u32)f2bf(acc[mt][nt][1]) << 16);
                u32 p1 = (u32)f2bf(acc[mt][nt][2]) | ((u32)f2bf(acc[mt][nt][3]) << 16);
                u32* dst = (u32*)(C + (size_t)col * ldc + row0);
                dst[0] = p0; dst[1] = p1;
            } else {
                float* C = (float*)Cout;
#pragma unroll
                for (int r = 0; r < 4; r++) {
                    size_t idx = (size_t)(row0 + r) * ldc + col;
                    C[idx] = acc[mt][nt][r] + res[idx];
                }
            }
        }
    }
}

// ---------------------------------------------------------------------------
// Flash attention, causal. Causal-fold pairing: grid (8, H), 512 threads
// (8 waves). Block x processes q-tiles {x, 15-x} (128 rows each) SEQUENTIALLY
// -> every block does exactly 34 KV-iterations (uniform load; old layout had a
// 2..32 iteration spread with the heavy blocks gating the kernel).
// Wave w owns 16 query rows of the current tile. K/V staged in double-buffered
// LDS; next KV block's global loads are issued at iteration start (regs) and
// written to the alternate buffer after PV -> HBM/L2 latency hidden under
// compute. P tile is wave-private (each wave writes+reads only its own 16
// rows) so no barrier between QK^T and PV: ONE barrier per iteration.
// q,k: (S, D) bf16 (post-rope). vt: (D, S) bf16 (V transposed). o: (S, D) bf16.
__global__ __launch_bounds__(512) void attn_kernel(
    const u16* __restrict__ q, const u16* __restrict__ k,
    const u16* __restrict__ vt, u16* __restrict__ o) {
    __shared__ u16 Ks[2][64][136];   // [buf][k_pos][d], +8 pad
    __shared__ u16 Vs[2][128][72];   // [buf][d][k_pos], +8 pad
    __shared__ u16 Ps[128][72];      // [q][k_pos], +8 pad (wave-private 16-row slices)
    const int h = blockIdx.y;
    const int tid = threadIdx.x, lane = tid & 63, wave = tid >> 6;
    const int gc = lane & 15, grp = lane >> 4;
    const float scale = 0.08838834764831843f;   // 1/sqrt(128)

    const int ti0 = blockIdx.x;          // light tile: 2*ti0+2 KV blocks
    const int ti1 = 15 - (int)blockIdx.x; // heavy tile: 2*ti1+2 KV blocks
    const int n0 = 2 * ti0 + 2;
    const int total = n0 + 2 * ti1 + 2;  // == 34 for every block

    // prologue: stage KV block j0=0 into buffer 0
    {
        uint4 kr0[2], vr0[2];
#pragma unroll
        for (int i = 0; i < 2; i++) {
            int c = tid + i * 512;
            kr0[i] = *(const uint4*)(k + (size_t)(c >> 4) * 4096 + h * 128 + (c & 15) * 8);
            vr0[i] = *(const uint4*)(vt + (size_t)(h * 128 + (c >> 3)) * 2048 + (c & 7) * 8);
        }
#pragma unroll
        for (int i = 0; i < 2; i++) {
            int c = tid + i * 512;
            *(uint4*)(&Ks[0][c >> 4][(c & 15) * 8]) = kr0[i];
            *(uint4*)(&Vs[0][c >> 3][(c & 7) * 8]) = vr0[i];
        }
    }
    __syncthreads();

    bf16x8 qf[4];
    f32x4 oacc[8];
    float mrun[4], lrun[4];
    const f32x4 fzero = {};
    int cur = 0;

    for (int it = 0; it < total; ++it) {
        const int t = (it >= n0) ? 1 : 0;
        const int local = t ? it - n0 : it;
        const int ti = t ? ti1 : ti0;
        const int j0 = local * 64;
        const int mw = ti * 128 + wave * 16;

        if (local == 0) {   // tile start: load Q frags, reset state
#pragma unroll
            for (int ks = 0; ks < 4; ks++)
                qf[ks] = *(const bf16x8*)(q + (size_t)(mw + gc) * 4096 + h * 128 +
                                          ks * 32 + grp * 8);
#pragma unroll
            for (int nd = 0; nd < 8; nd++) oacc[nd] = fzero;
#pragma unroll
            for (int r = 0; r < 4; r++) { mrun[r] = -1e30f; lrun[r] = 0.f; }
        }

        // issue next KV block's global loads NOW (written to LDS after PV)
        const int itn = it + 1;
        const bool havenext = itn < total;
        const int jn = (itn >= n0 ? itn - n0 : itn) * 64;
        uint4 kreg[2], vreg[2];
        if (havenext) {
#pragma unroll
            for (int i = 0; i < 2; i++) {
                int c = tid + i * 512;
                kreg[i] = *(const uint4*)(k + (size_t)(jn + (c >> 4)) * 4096 +
                                          h * 128 + (c & 15) * 8);
                vreg[i] = *(const uint4*)(vt + (size_t)(h * 128 + (c >> 3)) * 2048 +
                                          jn + (c & 7) * 8);
            }
        }

        // S = Q K^T
        f32x4 sfr[4] = {};
#pragma unroll
        for (int ks = 0; ks < 4; ks++) {
            bf16x8 kf[4];
#pragma unroll
            for (int nt = 0; nt < 4; nt++)
                kf[nt] = *(const bf16x8*)(&Ks[cur][nt * 16 + gc][ks * 32 + grp * 8]);
#pragma unroll
            for (int nt = 0; nt < 4; nt++)
                sfr[nt] = __builtin_amdgcn_mfma_f32_16x16x32_bf16(
                    qf[ks], kf[nt], sfr[nt], 0, 0, 0);
        }

        // causal mask (finite sentinel: keeps running max finite, exp -> 0)
        if (j0 + 63 > mw) {
#pragma unroll
            for (int nt = 0; nt < 4; nt++)
#pragma unroll
                for (int r = 0; r < 4; r++) {
                    int rowg = mw + grp * 4 + r;
                    int colg = j0 + nt * 16 + gc;
                    if (colg > rowg) sfr[nt][r] = -3.0e38f;
                }
        }

        // online softmax (fp32)
#pragma unroll
        for (int r = 0; r < 4; r++) {
            float rm = fmaxf(fmaxf(sfr[0][r], sfr[1][r]),
                             fmaxf(sfr[2][r], sfr[3][r])) * scale;
#pragma unroll
            for (int msk = 1; msk < 16; msk <<= 1)
                rm = fmaxf(rm, __shfl_xor(rm, msk, 64));
            float mnew = fmaxf(mrun[r], rm);
            float alpha = __expf(mrun[r] - mnew);
            mrun[r] = mnew;
            float rs = 0.f;
#pragma unroll
            for (int nt = 0; nt < 4; nt++) {
                float pv = __expf(sfr[nt][r] * scale - mnew);
                sfr[nt][r] = pv;
                rs += pv;
            }
#pragma unroll
            for (int msk = 1; msk < 16; msk <<= 1) rs += __shfl_xor(rs, msk, 64);
            lrun[r] = lrun[r] * alpha + rs;
#pragma unroll
            for (int nd = 0; nd < 8; nd++) oacc[nd][r] *= alpha;
        }

        // P: C-layout regs -> LDS A-layout. Wave-private rows -> no barrier
        // (same-wave LDS RAW ordered by lgkmcnt the compiler inserts).
#pragma unroll
        for (int nt = 0; nt < 4; nt++)
#pragma unroll
            for (int r = 0; r < 4; r++)
                Ps[wave * 16 + grp * 4 + r][nt * 16 + gc] = f2bf(sfr[nt][r]);

        // O += P V
#pragma unroll
        for (int ks2 = 0; ks2 < 2; ks2++) {
            bf16x8 pf = *(const bf16x8*)(&Ps[wave * 16 + gc][ks2 * 32 + grp * 8]);
#pragma unroll
            for (int nd = 0; nd < 8; nd++) {
                bf16x8 vf = *(const bf16x8*)(&Vs[cur][nd * 16 + gc][ks2 * 32 + grp * 8]);
                oacc[nd] = __builtin_amdgcn_mfma_f32_16x16x32_bf16(
                    pf, vf, oacc[nd], 0, 0, 0);
            }
        }

        // write prefetched KV into the alternate buffer (safe: last reads of
        // buf cur^1 were fenced by the previous iteration's barrier)
        if (havenext) {
#pragma unroll
            for (int i = 0; i < 2; i++) {
                int c = tid + i * 512;
                *(uint4*)(&Ks[cur ^ 1][c >> 4][(c & 15) * 8]) = kreg[i];
                *(uint4*)(&Vs[cur ^ 1][c >> 3][(c & 7) * 8]) = vreg[i];
            }
        }
        __syncthreads();
        cur ^= 1;

        // tile epilogue (last KV block of this tile)
        if (local == 2 * ti + 1) {
#pragma unroll
            for (int r = 0; r < 4; r++) {
                float invl = 1.f / lrun[r];
                int rowg = mw + grp * 4 + r;
#pragma unroll
                for (int nd = 0; nd < 8; nd++)
                    o[(size_t)rowg * 4096 + h * 128 + nd * 16 + gc] =
                        f2bf(oacc[nd][r] * invl);
            }
        }
    }
}

// ---------------------------------------------------------------------------
extern "C" void kernel_launch(void* const* d_in, const int* in_sizes, int n_in,
                              void* d_out, int out_size, void* d_ws, size_t ws_size,
                              hipStream_t stream) {
    (void)in_sizes; (void)n_in; (void)out_size; (void)ws_size;
    const float* x    = (const float*)d_in[0];
    const float* ln_w = (const float*)d_in[1];
    const float* ffw  = (const float*)d_in[2];
    const float* wq   = (const float*)d_in[3];
    const float* wk   = (const float*)d_in[4];
    const float* wv   = (const float*)d_in[5];
    const float* wo   = (const float*)d_in[6];
    const float* wg   = (const float*)d_in[7];
    const float* w1   = (const float*)d_in[8];
    const float* w2   = (const float*)d_in[9];
    float* out = (float*)d_out;

    char* p = (char*)d_ws;
    auto alloc = [&](size_t n) { char* r = p; p += (n + 255) & ~(size_t)255; return r; };
    u16* wqT = (u16*)alloc((size_t)4096 * 4096 * 2);
    u16* wkT = (u16*)alloc((size_t)4096 * 4096 * 2);
    u16* wvT = (u16*)alloc((size_t)4096 * 4096 * 2);
    u16* woT = (u16*)alloc((size_t)4096 * 4096 * 2);
    u16* wgT = (u16*)alloc((size_t)11008 * 4096 * 2);
    u16* w1T = (u16*)alloc((size_t)11008 * 4096 * 2);
    u16* w2T = (u16*)alloc((size_t)4096 * 11008 * 2);
    u16* xn  = (u16*)alloc((size_t)2048 * 4096 * 2);
    u16* qb  = (u16*)alloc((size_t)2048 * 4096 * 2);
    u16* kb  = (u16*)alloc((size_t)2048 * 4096 * 2);
    u16* vtb = (u16*)alloc((size_t)4096 * 2048 * 2);
    u16* ab  = (u16*)alloc((size_t)2048 * 4096 * 2);
    float* x2 = (float*)alloc((size_t)2048 * 4096 * 4);
    u16* xn2 = (u16*)alloc((size_t)2048 * 4096 * 2);
    u16* gb  = (u16*)alloc((size_t)2048 * 11008 * 2);
    u16* ub  = (u16*)alloc((size_t)2048 * 11008 * 2);

    dim3 tb(32, 8);
    transpose_f32_bf16<<<dim3(128, 64), tb, 0, stream>>>(wq, wqT, 4096, 4096);
    transpose_f32_bf16<<<dim3(128, 64), tb, 0, stream>>>(wk, wkT, 4096, 4096);
    transpose_f32_bf16<<<dim3(128, 64), tb, 0, stream>>>(wv, wvT, 4096, 4096);
    transpose_f32_bf16<<<dim3(128, 64), tb, 0, stream>>>(wo, woT, 4096, 4096);
    transpose_f32_bf16<<<dim3(344, 64), tb, 0, stream>>>(wg, wgT, 4096, 11008);
    transpose_f32_bf16<<<dim3(344, 64), tb, 0, stream>>>(w1, w1T, 4096, 11008);
    transpose_f32_bf16<<<dim3(128, 172), tb, 0, stream>>>(w2, w2T, 11008, 4096);

    rmsnorm_kernel<<<2048, 256, 0, stream>>>(x, ln_w, xn);

    gemm_bt<0><<<dim3(32, 16), 256, 0, stream>>>(xn, wqT, qb, nullptr,
                                                 2048, 4096, 4096, 4096, 4096, 4096);
    gemm_bt<0><<<dim3(32, 16), 256, 0, stream>>>(xn, wkT, kb, nullptr,
                                                 2048, 4096, 4096, 4096, 4096, 4096);
    gemm_bt<1><<<dim3(32, 16), 256, 0, stream>>>(xn, wvT, vtb, nullptr,
                                                 2048, 4096, 4096, 4096, 4096, 2048);

    rope_kernel<<<dim3(2048, 2), 256, 0, stream>>>(qb, kb);

    attn_kernel<<<dim3(8, 32), 512, 0, stream>>>(qb, kb, vtb, ab);

    gemm_bt<2><<<dim3(32, 16), 256, 0, stream>>>(ab, woT, x2, x,
                                                 2048, 4096, 4096, 4096, 4096, 4096);

    rmsnorm_kernel<<<2048, 256, 0, stream>>>(x2, ffw, xn2);

    gemm_bt<0><<<dim3(86, 16), 256, 0, stream>>>(xn2, wgT, gb, nullptr,
                                                 2048, 11008, 4096, 4096, 4096, 11008);
    gemm_bt<0><<<dim3(86, 16), 256, 0, stream>>>(xn2, w1T, ub, nullptr,
                                                 2048, 11008, 4096, 4096, 4096, 11008);

    silu_mul_kernel<<<11008, 256, 0, stream>>>(gb, ub, gb);

    gemm_bt<2><<<dim3(32, 16), 256, 0, stream>>>(gb, w2T, out, x2,
                                                 2048, 4096, 11008, 11008, 11008, 4096);
}